// Round 22
// baseline (228.221 us; speedup 1.0000x reference)
//
#include <hip/hip_runtime.h>
#include <stdint.h>

#define NPTS 8192
#define NPAIR 4096
#define NB 4
#define KNN 16
#define RQ 2          // queries (rows) per wave
#define CCAP 20       // per-lane private column capacity (u16 indices)
#define DCAP 256      // dense staging: fast path uses [0..127],[128..255] halves
#define MARGIN 1.5e-3f  // >> bound on |pk-approx - (exact d2 - qw)| (~2e-5)

typedef unsigned long long u64;
typedef unsigned int u32;
typedef unsigned short u16;
typedef float f32x2 __attribute__((ext_vector_type(2)));

__device__ __forceinline__ u32 f2ord(float f) {
    u32 b = __float_as_uint(f);
    return (b & 0x80000000u) ? ~b : (b | 0x80000000u);
}
__device__ __forceinline__ float ord2f(u32 u) {
    u32 b = (u & 0x80000000u) ? (u & 0x7fffffffu) : ~u;
    return __uint_as_float(b);
}
__device__ __forceinline__ u64 shflx64(u64 v, int m) {
    u32 lo = (u32)v, hi = (u32)(v >> 32);
    lo = __shfl_xor(lo, m, 64);
    hi = __shfl_xor(hi, m, 64);
    return ((u64)hi << 32) | lo;
}

// Pair-packed SoA: pos8[(b*NPAIR+m)*2+0] = {x0,x1,y0,y1}, +1 = {z0,z1,sq0,sq1}.
// sq via mul-add chain (np.sum(p*p)): ((x*x + y*y) + z*z), all _rn.
__global__ __launch_bounds__(256) void pack_kernel(const float* __restrict__ pos,
                                                   float4* __restrict__ pos8) {
    int t = blockIdx.x * 256 + threadIdx.x;   // 0..16383
    int b = t >> 12;
    int m = t & (NPAIR - 1);
    const float* p = pos + (size_t)b * 3 * NPTS;
    float2 x = *(const float2*)&p[2 * m];
    float2 y = *(const float2*)&p[NPTS + 2 * m];
    float2 z = *(const float2*)&p[2 * NPTS + 2 * m];
    float s0 = __fadd_rn(__fadd_rn(__fmul_rn(x.x, x.x), __fmul_rn(y.x, y.x)), __fmul_rn(z.x, z.x));
    float s1 = __fadd_rn(__fadd_rn(__fmul_rn(x.y, x.y), __fmul_rn(y.y, y.y)), __fmul_rn(z.y, z.y));
    pos8[2 * t]     = make_float4(x.x, x.y, y.x, y.y);
    pos8[2 * t + 1] = make_float4(z.x, z.y, s0, s1);
}

// exact reference d2 for stored candidate index (BLAS-fma dot, _rn combine)
#define RECOMP(r, idx, d2out)                                                           \
    { int _m = (int)(idx) >> 1, _h = (int)(idx) & 1;                                    \
      float4 _a = P8[2 * _m], _c = P8[2 * _m + 1];                                      \
      float _px = _h ? _a.y : _a.x, _py = _h ? _a.w : _a.z;                             \
      float _pz = _h ? _c.y : _c.x, _pw = _h ? _c.w : _c.z;                             \
      float _dot = __fmaf_rn(qz[r], _pz, __fmaf_rn(qy[r], _py, __fmul_rn(qx[r], _px))); \
      d2out = __fsub_rn(__fadd_rn(qw[r], _pw), __fmul_rn(2.0f, _dot)); }

// pk-approx filter + per-lane LDS-column append (no ballots in hot loop).
#define PROC(Av, Cv, mm)                                                                \
    {                                                                                   \
        f32x2 x01 = {(Av).x, (Av).y}, y01 = {(Av).z, (Av).w};                           \
        f32x2 z01 = {(Cv).x, (Cv).y}, sq01 = {(Cv).z, (Cv).w};                          \
        _Pragma("unroll")                                                               \
        for (int r = 0; r < RQ; ++r) {                                                  \
            f32x2 dot01 = __builtin_elementwise_fma(                                    \
                qzv[r], z01, __builtin_elementwise_fma(qyv[r], y01, qxv[r] * x01));     \
            f32x2 val01 = __builtin_elementwise_fma(n2v, dot01, sq01);                  \
            if (val01.x < Tm[r]) { col[wv][r][c[r]][lane] = (u16)(2 * (mm));     c[r]++; } \
            if (val01.y < Tm[r]) { col[wv][r][c[r]][lane] = (u16)(2 * (mm) + 1); c[r]++; } \
        }                                                                               \
    }

#define TRIGC()                                                                         \
    {                                                                                   \
        if (__ballot(c[0] > 16)) tighten(0);                                            \
        if (__ballot(c[1] > 16)) tighten(1);                                            \
    }

// One wave serves RQ=2 rows. Scan identical to r21 (183 us baseline). The
// bootstrap and final phases now run BOTH queries' serial shuffle chains
// interleaved (dual-stream): the two chains are independent, so 2-way ILP
// inside the latency chain makes two sorts cost ~one sort's latency.
// All pruning invariants unchanged (>=16 strictly-smaller-key witnesses for
// every discarded candidate); final ranking uses exact _rn keys only.
__global__ __launch_bounds__(256) void knn_kernel(const float4* __restrict__ pos8,
                                                  float* __restrict__ out) {
    __shared__ u16 col[4][RQ][CCAP][64];
    __shared__ u16 dense[4][DCAP];
    const int lane = threadIdx.x & 63;
    const int wv = threadIdx.x >> 6;
    const int rowbase = blockIdx.x * (4 * RQ) + wv * RQ;   // 8 rows per block
    const int b = rowbase >> 13;
    const int ib = rowbase & (NPTS - 1);
    const float4* __restrict__ P8 = pos8 + (size_t)b * NPAIR * 2;
    const u64 below = (1ull << lane) - 1ull;

    float qx[RQ], qy[RQ], qz[RQ], qw[RQ];
    {
        int m = ib >> 1;   // ib even: both rows come from one pair
        float4 a = P8[2 * m], cc = P8[2 * m + 1];
        qx[0] = a.x; qy[0] = a.z; qz[0] = cc.x; qw[0] = cc.z;
        qx[1] = a.y; qy[1] = a.w; qz[1] = cc.y; qw[1] = cc.w;
    }
    f32x2 qxv[RQ], qyv[RQ], qzv[RQ];
#pragma unroll
    for (int r = 0; r < RQ; ++r) {
        qxv[r] = (f32x2){qx[r], qx[r]};
        qyv[r] = (f32x2){qy[r], qy[r]};
        qzv[r] = (f32x2){qz[r], qz[r]};
    }
    const f32x2 n2v = {-2.0f, -2.0f};

    float Tm[RQ];   // filter threshold on approx val (= d2 - qw domain)
    int c[RQ];      // per-lane column count

    // dual 16th-smallest of 64 per-lane f32 values (interleaved bitonic)
    auto rank16f2 = [&](float& a, float& bb) {
#pragma unroll
        for (int k = 2; k <= 64; k <<= 1)
#pragma unroll
            for (int j = k >> 1; j >= 1; j >>= 1) {
                float oa = __shfl_xor(a, j, 64);
                float ob = __shfl_xor(bb, j, 64);
                bool up = ((lane & k) == 0) == ((lane & j) == 0);
                a  = (up ? (a < oa)  : (a > oa))  ? a  : oa;
                bb = (up ? (bb < ob) : (bb > ob)) ? bb : ob;
            }
        a = __shfl(a, 15, 64);
        bb = __shfl(bb, 15, 64);
    };

    // exact tighten: T' = 16th lane-min of exact d2, lane-local compact + trim.
    auto tighten = [&](int r) {
        u32 mn = 0xFFFFFFFFu;
#pragma unroll
        for (int t = 0; t < CCAP; ++t) {
            if (t < c[r]) {
                u32 idx = (u32)col[wv][r][t][lane];
                float d2; RECOMP(r, idx, d2);
                u32 o = f2ord(d2);
                mn = o < mn ? o : mn;
            }
        }
        u32 v = mn;
#pragma unroll
        for (int k = 2; k <= 64; k <<= 1)
#pragma unroll
            for (int j = k >> 1; j >= 1; j >>= 1) {
                u32 o = (u32)__shfl_xor((int)v, j, 64);
                bool up = ((lane & k) == 0) == ((lane & j) == 0);
                v = (up ? (v < o) : (v > o)) ? v : o;
            }
        u32 ordK = (u32)__shfl((int)v, 15, 64);
        int nc = 0;
#pragma unroll
        for (int t = 0; t < CCAP; ++t) {
            if (t < c[r]) {
                u32 idx = (u32)col[wv][r][t][lane];
                float d2; RECOMP(r, idx, d2);
                if (f2ord(d2) <= ordK) { col[wv][r][nc][lane] = (u16)idx; ++nc; }
            }
        }
        c[r] = nc;
        // trim lane to its 16 smallest keys (dropped entry has >=16 smaller in-lane)
#pragma unroll 1
        for (int it = 0; it < CCAP - 16; ++it) {
            if (c[r] > 16) {
                u64 mx = 0; int mt = 0;
#pragma unroll
                for (int t = 0; t < CCAP; ++t) {
                    if (t < c[r]) {
                        u32 idx = (u32)col[wv][r][t][lane];
                        float d2; RECOMP(r, idx, d2);
                        u64 key = ((u64)f2ord(d2) << 13) | idx;
                        if (key > mx) { mx = key; mt = t; }
                    }
                }
                col[wv][r][mt][lane] = col[wv][r][c[r] - 1][lane];
                c[r] -= 1;
            }
        }
        Tm[r] = fminf(Tm[r], (ord2f(ordK) - qw[r]) + MARGIN);  // monotone
    };

    // ---- bootstrap: pairs 0..255 (512 cands) in registers; dual rank16 ----
    {
        f32x2 vv[RQ][4];
        float mn[RQ];
        {
            float4 A[4], C[4];
#pragma unroll
            for (int s = 0; s < 4; ++s) {
                int m = s * 64 + lane;
                A[s] = P8[2 * m];
                C[s] = P8[2 * m + 1];
            }
#pragma unroll
            for (int r = 0; r < RQ; ++r) {
                mn[r] = __uint_as_float(0x7f800000u);   // +inf
#pragma unroll
                for (int s = 0; s < 4; ++s) {
                    f32x2 x01 = {A[s].x, A[s].y}, y01 = {A[s].z, A[s].w};
                    f32x2 z01 = {C[s].x, C[s].y}, sq01 = {C[s].z, C[s].w};
                    vv[r][s] = __builtin_elementwise_fma(
                        n2v, __builtin_elementwise_fma(qzv[r], z01,
                             __builtin_elementwise_fma(qyv[r], y01, qxv[r] * x01)), sq01);
                    mn[r] = fminf(mn[r], fminf(vv[r][s].x, vv[r][s].y));
                }
            }
        }
        rank16f2(mn[0], mn[1]);   // both V16 in one interleaved chain
#pragma unroll
        for (int r = 0; r < RQ; ++r) {
            Tm[r] = mn[r] + 2.0f * MARGIN;
            c[r] = 0;
#pragma unroll
            for (int s = 0; s < 4; ++s) {
                int m = s * 64 + lane;
                if (vv[r][s].x < Tm[r]) { col[wv][r][c[r]][lane] = (u16)(2 * m);     c[r]++; }
                if (vv[r][s].y < Tm[r]) { col[wv][r][c[r]][lane] = (u16)(2 * m + 1); c[r]++; }
            }
        }
    }

    // ---- steady scan: g = 1..15, 4 pair-slots; trigger check every 2 slots ----
#pragma unroll 1
    for (int g = 1; g < 16; ++g) {
        TRIGC();   // c <= 16 after; +4 appends max before the mid-check
        int base = g * 256;
        float4 A[4], C[4];
#pragma unroll
        for (int s = 0; s < 4; ++s) {
            int m = base + s * 64 + lane;
            A[s] = P8[2 * m];
            C[s] = P8[2 * m + 1];
        }
        PROC(A[0], C[0], base + lane);
        PROC(A[1], C[1], base + 64 + lane);
        TRIGC();   // mid-group check keeps c <= CCAP = 20
        PROC(A[2], C[2], base + 128 + lane);
        PROC(A[3], C[3], base + 192 + lane);
    }

    // ---- final: dual-stream fast path (both queries' chains interleaved) ----
    {
        int s0 = c[0], s1 = c[1];
#pragma unroll
        for (int s2 = 1; s2 < 64; s2 <<= 1) {
            s0 += __shfl_xor(s0, s2, 64);
            s1 += __shfl_xor(s1, s2, 64);
        }
        if (s0 > 64) { tighten(0); s0 = c[0];
#pragma unroll
            for (int s2 = 1; s2 < 64; s2 <<= 1) s0 += __shfl_xor(s0, s2, 64);
        }
        if (s1 > 64) { tighten(1); s1 = c[1];
#pragma unroll
            for (int s2 = 1; s2 < 64; s2 <<= 1) s1 += __shfl_xor(s1, s2, 64);
        }

        if (s0 <= 64 && s1 <= 64) {
            // interleaved gather: query 0 -> dense[0..63], query 1 -> dense[128..191]
            int nc0 = 0, nc1 = 0;
#pragma unroll 1
            for (int t = 0; t < CCAP; ++t) {
                bool v0 = t < c[0], v1 = t < c[1];
                u64 b0 = __ballot(v0), b1 = __ballot(v1);
                if (!(b0 | b1)) break;
                if (v0) dense[wv][nc0 + (int)__popcll(b0 & below)] = col[wv][0][t][lane];
                if (v1) dense[wv][128 + nc1 + (int)__popcll(b1 & below)] = col[wv][1][t][lane];
                nc0 += (int)__popcll(b0);
                nc1 += (int)__popcll(b1);
            }
            // dual RECOMP (all loads batched) + dual interleaved u64 sort-64
            bool va = lane < nc0, vb = lane < nc1;
            u32 ia = va ? (u32)dense[wv][lane] : 0u;
            u32 ibx = vb ? (u32)dense[wv][128 + lane] : 0u;
            float da, db;
            RECOMP(0, ia, da);
            RECOMP(1, ibx, db);
            u64 v0 = va ? (((u64)f2ord(da) << 13) | ia) : ~0ULL;
            u64 v1 = vb ? (((u64)f2ord(db) << 13) | ibx) : ~0ULL;
#pragma unroll
            for (int k = 2; k <= 64; k <<= 1)
#pragma unroll
                for (int j = k >> 1; j >= 1; j >>= 1) {
                    u64 o0 = shflx64(v0, j);
                    u64 o1 = shflx64(v1, j);
                    bool up = ((lane & k) == 0) == ((lane & j) == 0);
                    v0 = (up ? (v0 < o0) : (v0 > o0)) ? v0 : o0;
                    v1 = (up ? (v1 < o1) : (v1 > o1)) ? v1 : o1;
                }
            if (lane < KNN) {
                size_t o1 = (size_t)(b * KNN + lane) * NPTS + ib;
                out[o1] = (float)(u32)(v0 & (u64)(NPTS - 1));
                out[(size_t)NB * KNN * NPTS + o1] = ord2f((u32)(v0 >> 13));
                size_t o2 = (size_t)(b * KNN + lane) * NPTS + ib + 1;
                out[o2] = (float)(u32)(v1 & (u64)(NPTS - 1));
                out[(size_t)NB * KNN * NPTS + o2] = ord2f((u32)(v1 >> 13));
            }
        } else {
            // rare adversarial path: sequential per-query (r21 code)
#pragma unroll 1
            for (int r = 0; r < RQ; ++r) {
                int nc = 0;
#pragma unroll 1
                for (int t = 0; t < CCAP; ++t) {
                    bool valid = t < c[r];
                    u64 bal = __ballot(valid);
                    if (!bal) break;
                    if (valid) dense[wv][nc + (int)__popcll(bal & below)] = col[wv][r][t][lane];
                    nc += (int)__popcll(bal);
                }
                u64 myk = ~0ULL;
                if (nc <= 64) {
                    bool valid = lane < nc;
                    u32 idx = valid ? (u32)dense[wv][lane] : 0u;
                    float d2; RECOMP(r, idx, d2);
                    u64 v = valid ? (((u64)f2ord(d2) << 13) | idx) : ~0ULL;
#pragma unroll
                    for (int k = 2; k <= 64; k <<= 1)
#pragma unroll
                        for (int j = k >> 1; j >= 1; j >>= 1) {
                            u64 o = shflx64(v, j);
                            bool up = ((lane & k) == 0) == ((lane & j) == 0);
                            v = (up ? (v < o) : (v > o)) ? v : o;
                        }
                    myk = v;
                } else {
                    u64 s4[4];
#pragma unroll
                    for (int t = 0; t < 4; ++t) {
                        int bi = t * 64 + lane;
                        bool valid = bi < nc;
                        u32 idx = valid ? (u32)dense[wv][bi] : 0u;
                        float d2; RECOMP(r, idx, d2);
                        s4[t] = valid ? (((u64)f2ord(d2) << 13) | idx) : ~0ULL;
                    }
#pragma unroll 1
                    for (int rr = 0; rr < KNN; ++rr) {
                        u64 lm = s4[0];
#pragma unroll
                        for (int t = 1; t < 4; ++t) lm = s4[t] < lm ? s4[t] : lm;
                        u64 mm = lm;
#pragma unroll
                        for (int s2 = 1; s2 < 64; s2 <<= 1) { u64 o = shflx64(mm, s2); mm = o < mm ? o : mm; }
#pragma unroll
                        for (int t = 0; t < 4; ++t) s4[t] = (s4[t] == mm) ? ~0ULL : s4[t];
                        if (lane == rr) myk = mm;
                    }
                }
                if (lane < KNN) {
                    int iq = ib + r;
                    size_t o1 = (size_t)(b * KNN + lane) * NPTS + iq;
                    out[o1] = (float)(u32)(myk & (u64)(NPTS - 1));
                    out[(size_t)NB * KNN * NPTS + o1] = ord2f((u32)(myk >> 13));
                }
            }
        }
    }
}

extern "C" void kernel_launch(void* const* d_in, const int* in_sizes, int n_in,
                              void* d_out, int out_size, void* d_ws, size_t ws_size,
                              hipStream_t stream) {
    const float* pos = (const float*)d_in[0];
    float* out = (float*)d_out;
    float4* pos8 = (float4*)d_ws;   // 4*4096*2*16 B = 512 KB scratch

    pack_kernel<<<dim3(NB * NPAIR / 256), dim3(256), 0, stream>>>(pos, pos8);
    knn_kernel<<<dim3(NB * NPTS / 8), dim3(256), 0, stream>>>(pos8, out);
}

// Round 23
// 171.595 us; speedup vs baseline: 1.3300x; 1.3300x over previous
//
#include <hip/hip_runtime.h>
#include <stdint.h>

#define NPTS 8192
#define NPAIR 4096
#define NB 4
#define KNN 16
#define RQ 2          // queries (rows) per wave
#define CCAP 20       // per-lane private column capacity (u16 indices)
#define DCAP 256      // dense staging for final select (16 lanes * 16 entries)
#define MARGIN 1.5e-3f  // >> bound on |pk-approx - (exact d2 - qw)| (~2e-5)

typedef unsigned long long u64;
typedef unsigned int u32;
typedef unsigned short u16;
typedef float f32x2 __attribute__((ext_vector_type(2)));

__device__ __forceinline__ u32 f2ord(float f) {
    u32 b = __float_as_uint(f);
    return (b & 0x80000000u) ? ~b : (b | 0x80000000u);
}
__device__ __forceinline__ float ord2f(u32 u) {
    u32 b = (u & 0x80000000u) ? (u & 0x7fffffffu) : ~u;
    return __uint_as_float(b);
}
__device__ __forceinline__ u64 shflx64(u64 v, int m) {
    u32 lo = (u32)v, hi = (u32)(v >> 32);
    lo = __shfl_xor(lo, m, 64);
    hi = __shfl_xor(hi, m, 64);
    return ((u64)hi << 32) | lo;
}

// Pair-packed SoA: pos8[(b*NPAIR+m)*2+0] = {x0,x1,y0,y1}, +1 = {z0,z1,sq0,sq1}.
// sq via mul-add chain (np.sum(p*p)): ((x*x + y*y) + z*z), all _rn.
__global__ __launch_bounds__(256) void pack_kernel(const float* __restrict__ pos,
                                                   float4* __restrict__ pos8) {
    int t = blockIdx.x * 256 + threadIdx.x;   // 0..16383
    int b = t >> 12;
    int m = t & (NPAIR - 1);
    const float* p = pos + (size_t)b * 3 * NPTS;
    float2 x = *(const float2*)&p[2 * m];
    float2 y = *(const float2*)&p[NPTS + 2 * m];
    float2 z = *(const float2*)&p[2 * NPTS + 2 * m];
    float s0 = __fadd_rn(__fadd_rn(__fmul_rn(x.x, x.x), __fmul_rn(y.x, y.x)), __fmul_rn(z.x, z.x));
    float s1 = __fadd_rn(__fadd_rn(__fmul_rn(x.y, x.y), __fmul_rn(y.y, y.y)), __fmul_rn(z.y, z.y));
    pos8[2 * t]     = make_float4(x.x, x.y, y.x, y.y);
    pos8[2 * t + 1] = make_float4(z.x, z.y, s0, s1);
}

// exact reference d2 for stored candidate index (BLAS-fma dot, _rn combine)
#define RECOMP(r, idx, d2out)                                                           \
    { int _m = (int)(idx) >> 1, _h = (int)(idx) & 1;                                    \
      float4 _a = P8[2 * _m], _c = P8[2 * _m + 1];                                      \
      float _px = _h ? _a.y : _a.x, _py = _h ? _a.w : _a.z;                             \
      float _pz = _h ? _c.y : _c.x, _pw = _h ? _c.w : _c.z;                             \
      float _dot = __fmaf_rn(qz[r], _pz, __fmaf_rn(qy[r], _py, __fmul_rn(qx[r], _px))); \
      d2out = __fsub_rn(__fadd_rn(qw[r], _pw), __fmul_rn(2.0f, _dot)); }

// BRANCHLESS append: unconditional LDS write at slot c[r], conditional
// increment. A rejected candidate's write is overwritten by the next
// candidate (slot not committed). Reads are always bounded by c[r], so
// uncommitted slots are never observed. Max write index: post-TRIGC c<=16,
// <=4 writes between checks -> 19 < CCAP=20.
#define PROC(Av, Cv, mm)                                                                \
    {                                                                                   \
        f32x2 x01 = {(Av).x, (Av).y}, y01 = {(Av).z, (Av).w};                           \
        f32x2 z01 = {(Cv).x, (Cv).y}, sq01 = {(Cv).z, (Cv).w};                          \
        _Pragma("unroll")                                                               \
        for (int r = 0; r < RQ; ++r) {                                                  \
            f32x2 dot01 = __builtin_elementwise_fma(                                    \
                qzv[r], z01, __builtin_elementwise_fma(qyv[r], y01, qxv[r] * x01));     \
            f32x2 val01 = __builtin_elementwise_fma(n2v, dot01, sq01);                  \
            col[wv][r][c[r]][lane] = (u16)(2 * (mm));                                   \
            c[r] += (val01.x < Tm[r]) ? 1 : 0;                                          \
            col[wv][r][c[r]][lane] = (u16)(2 * (mm) + 1);                               \
            c[r] += (val01.y < Tm[r]) ? 1 : 0;                                          \
        }                                                                               \
    }

#define TRIGC()                                                                         \
    {                                                                                   \
        if (__ballot(c[0] > 16)) tighten(0);                                            \
        if (__ballot(c[1] > 16)) tighten(1);                                            \
    }

// One wave serves RQ=2 rows. Scan: pk-approx conservative filter into per-lane
// LDS columns (branchless append); exact RECOMP only at tighten (trigger/final).
// Invariant: Tm always has >=16 buffer entries with exact (d2-qw) <= Tm-MARGIN;
// every prune/discard leaves >=16 strictly-smaller (d2,idx) keys (witnesses
// precede future candidates in index, so d2-ties lose). Final ranking: exact keys.
__global__ __launch_bounds__(256) void knn_kernel(const float4* __restrict__ pos8,
                                                  float* __restrict__ out) {
    __shared__ u16 col[4][RQ][CCAP][64];
    __shared__ u16 dense[4][DCAP];
    const int lane = threadIdx.x & 63;
    const int wv = threadIdx.x >> 6;
    const int rowbase = blockIdx.x * (4 * RQ) + wv * RQ;   // 8 rows per block
    const int b = rowbase >> 13;
    const int ib = rowbase & (NPTS - 1);
    const float4* __restrict__ P8 = pos8 + (size_t)b * NPAIR * 2;
    const u64 below = (1ull << lane) - 1ull;

    float qx[RQ], qy[RQ], qz[RQ], qw[RQ];
    {
        int m = ib >> 1;   // ib even: both rows come from one pair
        float4 a = P8[2 * m], cc = P8[2 * m + 1];
        qx[0] = a.x; qy[0] = a.z; qz[0] = cc.x; qw[0] = cc.z;
        qx[1] = a.y; qy[1] = a.w; qz[1] = cc.y; qw[1] = cc.w;
    }
    f32x2 qxv[RQ], qyv[RQ], qzv[RQ];
#pragma unroll
    for (int r = 0; r < RQ; ++r) {
        qxv[r] = (f32x2){qx[r], qx[r]};
        qyv[r] = (f32x2){qy[r], qy[r]};
        qzv[r] = (f32x2){qz[r], qz[r]};
    }
    const f32x2 n2v = {-2.0f, -2.0f};

    float Tm[RQ];   // filter threshold on approx val (= d2 - qw domain)
    int c[RQ];      // per-lane column count

    // 16th-smallest of 64 per-lane f32 values via bitonic sort + broadcast
    auto rank16f = [&](float v) -> float {
#pragma unroll
        for (int k = 2; k <= 64; k <<= 1)
#pragma unroll
            for (int j = k >> 1; j >= 1; j >>= 1) {
                float o = __shfl_xor(v, j, 64);
                bool up = ((lane & k) == 0) == ((lane & j) == 0);
                v = (up ? (v < o) : (v > o)) ? v : o;
            }
        return __shfl(v, 15, 64);
    };

    // exact tighten: T' = 16th lane-min of exact d2, lane-local compact + trim.
    auto tighten = [&](int r) {
        u32 mn = 0xFFFFFFFFu;
#pragma unroll
        for (int t = 0; t < CCAP; ++t) {
            if (t < c[r]) {
                u32 idx = (u32)col[wv][r][t][lane];
                float d2; RECOMP(r, idx, d2);
                u32 o = f2ord(d2);
                mn = o < mn ? o : mn;
            }
        }
        u32 v = mn;
#pragma unroll
        for (int k = 2; k <= 64; k <<= 1)
#pragma unroll
            for (int j = k >> 1; j >= 1; j >>= 1) {
                u32 o = (u32)__shfl_xor((int)v, j, 64);
                bool up = ((lane & k) == 0) == ((lane & j) == 0);
                v = (up ? (v < o) : (v > o)) ? v : o;
            }
        u32 ordK = (u32)__shfl((int)v, 15, 64);
        int nc = 0;
#pragma unroll
        for (int t = 0; t < CCAP; ++t) {
            if (t < c[r]) {
                u32 idx = (u32)col[wv][r][t][lane];
                float d2; RECOMP(r, idx, d2);
                if (f2ord(d2) <= ordK) { col[wv][r][nc][lane] = (u16)idx; ++nc; }
            }
        }
        c[r] = nc;
        // trim lane to its 16 smallest keys (dropped entry has >=16 smaller in-lane)
#pragma unroll 1
        for (int it = 0; it < CCAP - 16; ++it) {
            if (c[r] > 16) {
                u64 mx = 0; int mt = 0;
#pragma unroll
                for (int t = 0; t < CCAP; ++t) {
                    if (t < c[r]) {
                        u32 idx = (u32)col[wv][r][t][lane];
                        float d2; RECOMP(r, idx, d2);
                        u64 key = ((u64)f2ord(d2) << 13) | idx;
                        if (key > mx) { mx = key; mt = t; }
                    }
                }
                col[wv][r][mt][lane] = col[wv][r][c[r] - 1][lane];
                c[r] -= 1;
            }
        }
        Tm[r] = fminf(Tm[r], (ord2f(ordK) - qw[r]) + MARGIN);  // monotone
    };

    // ---- bootstrap: pairs 0..255 (512 cands) fully in registers ----
    // Tm = rank16(lane-min of 8 approx vals) + 2*MARGIN: >=16 distinct-lane
    // witnesses with approx <= V16 < Tm are all appended below; their exact
    // <= V16 + eps. Zero RECOMP traffic.
    {
        float4 A[4], C[4];
#pragma unroll
        for (int s = 0; s < 4; ++s) {
            int m = s * 64 + lane;
            A[s] = P8[2 * m];
            C[s] = P8[2 * m + 1];
        }
#pragma unroll
        for (int r = 0; r < RQ; ++r) {
            f32x2 vv[4];
            float mn = __uint_as_float(0x7f800000u);   // +inf
#pragma unroll
            for (int s = 0; s < 4; ++s) {
                f32x2 x01 = {A[s].x, A[s].y}, y01 = {A[s].z, A[s].w};
                f32x2 z01 = {C[s].x, C[s].y}, sq01 = {C[s].z, C[s].w};
                vv[s] = __builtin_elementwise_fma(
                    n2v, __builtin_elementwise_fma(qzv[r], z01,
                         __builtin_elementwise_fma(qyv[r], y01, qxv[r] * x01)), sq01);
                mn = fminf(mn, fminf(vv[s].x, vv[s].y));
            }
            float V16 = rank16f(mn);
            Tm[r] = V16 + 2.0f * MARGIN;
            c[r] = 0;
#pragma unroll
            for (int s = 0; s < 4; ++s) {
                int m = s * 64 + lane;
                col[wv][r][c[r]][lane] = (u16)(2 * m);
                c[r] += (vv[s].x < Tm[r]) ? 1 : 0;
                col[wv][r][c[r]][lane] = (u16)(2 * m + 1);
                c[r] += (vv[s].y < Tm[r]) ? 1 : 0;
            }
        }
    }

    // ---- steady scan: g = 1..15, 4 pair-slots; trigger check every 2 slots ----
#pragma unroll 1
    for (int g = 1; g < 16; ++g) {
        TRIGC();   // c <= 16 after; +4 writes max before the mid-check
        int base = g * 256;
        float4 A[4], C[4];
#pragma unroll
        for (int s = 0; s < 4; ++s) {
            int m = base + s * 64 + lane;
            A[s] = P8[2 * m];
            C[s] = P8[2 * m + 1];
        }
        PROC(A[0], C[0], base + lane);
        PROC(A[1], C[1], base + 64 + lane);
        TRIGC();   // mid-group check keeps write index < CCAP = 20
        PROC(A[2], C[2], base + 128 + lane);
        PROC(A[3], C[3], base + 192 + lane);
    }

    // ---- final per query (sequential in r -> dense reuse is safe) ----
#pragma unroll
    for (int r = 0; r < RQ; ++r) {
        int sum = c[r];
#pragma unroll
        for (int s2 = 1; s2 < 64; s2 <<= 1) sum += __shfl_xor(sum, s2, 64);
        if (sum > 64) tighten(r);   // bounds survivors to <= 256 (16 lanes x 16)
        int nc = 0;
#pragma unroll 1
        for (int t = 0; t < CCAP; ++t) {
            bool valid = t < c[r];
            u64 bal = __ballot(valid);
            if (!bal) break;
            if (valid) dense[wv][nc + (int)__popcll(bal & below)] = col[wv][r][t][lane];
            nc += (int)__popcll(bal);
        }
        u64 myk = ~0ULL;
        if (nc <= 64) {
            bool valid = lane < nc;
            u32 idx = valid ? (u32)dense[wv][lane] : 0u;
            float d2; RECOMP(r, idx, d2);
            u64 v = valid ? (((u64)f2ord(d2) << 13) | idx) : ~0ULL;
#pragma unroll
            for (int k = 2; k <= 64; k <<= 1)
#pragma unroll
                for (int j = k >> 1; j >= 1; j >>= 1) {
                    u64 o = shflx64(v, j);
                    bool up = ((lane & k) == 0) == ((lane & j) == 0);
                    v = (up ? (v < o) : (v > o)) ? v : o;
                }
            myk = v;   // lane holds rank = lane
        } else {
            // rare path: exact extract-min tournament over <= 256 keys
            u64 s4[4];
#pragma unroll
            for (int t = 0; t < 4; ++t) {
                int bi = t * 64 + lane;
                bool valid = bi < nc;
                u32 idx = valid ? (u32)dense[wv][bi] : 0u;
                float d2; RECOMP(r, idx, d2);
                s4[t] = valid ? (((u64)f2ord(d2) << 13) | idx) : ~0ULL;
            }
#pragma unroll 1
            for (int rr = 0; rr < KNN; ++rr) {
                u64 lm = s4[0];
#pragma unroll
                for (int t = 1; t < 4; ++t) lm = s4[t] < lm ? s4[t] : lm;
                u64 mm = lm;
#pragma unroll
                for (int s2 = 1; s2 < 64; s2 <<= 1) { u64 o = shflx64(mm, s2); mm = o < mm ? o : mm; }
#pragma unroll
                for (int t = 0; t < 4; ++t) s4[t] = (s4[t] == mm) ? ~0ULL : s4[t];
                if (lane == rr) myk = mm;
            }
        }
        if (lane < KNN) {
            int iq = ib + r;
            size_t o1 = (size_t)(b * KNN + lane) * NPTS + iq;
            out[o1] = (float)(u32)(myk & (u64)(NPTS - 1));
            out[(size_t)NB * KNN * NPTS + o1] = ord2f((u32)(myk >> 13));
        }
    }
}

extern "C" void kernel_launch(void* const* d_in, const int* in_sizes, int n_in,
                              void* d_out, int out_size, void* d_ws, size_t ws_size,
                              hipStream_t stream) {
    const float* pos = (const float*)d_in[0];
    float* out = (float*)d_out;
    float4* pos8 = (float4*)d_ws;   // 4*4096*2*16 B = 512 KB scratch

    pack_kernel<<<dim3(NB * NPAIR / 256), dim3(256), 0, stream>>>(pos, pos8);
    knn_kernel<<<dim3(NB * NPTS / 8), dim3(256), 0, stream>>>(pos8, out);
}

// Round 24
// 165.595 us; speedup vs baseline: 1.3782x; 1.0362x over previous
//
#include <hip/hip_runtime.h>
#include <stdint.h>

#define NPTS 8192
#define NPAIR 4096
#define NB 4
#define KNN 16
#define RQ 2          // queries (rows) per wave
#define CCAP 20       // per-lane private column capacity (u16 PAIR indices)
#define DCAP 256      // dense staging for final select (pair entries)
#define MARGIN 1.5e-3f  // >> bound on |pk-approx - (exact d2 - qw)| (~2e-5)

typedef unsigned long long u64;
typedef unsigned int u32;
typedef unsigned short u16;
typedef float f32x2 __attribute__((ext_vector_type(2)));

__device__ __forceinline__ u32 f2ord(float f) {
    u32 b = __float_as_uint(f);
    return (b & 0x80000000u) ? ~b : (b | 0x80000000u);
}
__device__ __forceinline__ float ord2f(u32 u) {
    u32 b = (u & 0x80000000u) ? (u & 0x7fffffffu) : ~u;
    return __uint_as_float(b);
}
__device__ __forceinline__ u64 shflx64(u64 v, int m) {
    u32 lo = (u32)v, hi = (u32)(v >> 32);
    lo = __shfl_xor(lo, m, 64);
    hi = __shfl_xor(hi, m, 64);
    return ((u64)hi << 32) | lo;
}

// Pair-packed SoA: pos8[(b*NPAIR+m)*2+0] = {x0,x1,y0,y1}, +1 = {z0,z1,sq0,sq1}.
// sq via mul-add chain (np.sum(p*p)): ((x*x + y*y) + z*z), all _rn.
__global__ __launch_bounds__(256) void pack_kernel(const float* __restrict__ pos,
                                                   float4* __restrict__ pos8) {
    int t = blockIdx.x * 256 + threadIdx.x;   // 0..16383
    int b = t >> 12;
    int m = t & (NPAIR - 1);
    const float* p = pos + (size_t)b * 3 * NPTS;
    float2 x = *(const float2*)&p[2 * m];
    float2 y = *(const float2*)&p[NPTS + 2 * m];
    float2 z = *(const float2*)&p[2 * NPTS + 2 * m];
    float s0 = __fadd_rn(__fadd_rn(__fmul_rn(x.x, x.x), __fmul_rn(y.x, y.x)), __fmul_rn(z.x, z.x));
    float s1 = __fadd_rn(__fadd_rn(__fmul_rn(x.y, x.y), __fmul_rn(y.y, y.y)), __fmul_rn(z.y, z.y));
    pos8[2 * t]     = make_float4(x.x, x.y, y.x, y.y);
    pos8[2 * t + 1] = make_float4(z.x, z.y, s0, s1);
}

// exact reference d2 for BOTH candidates of pair m (one shared load pair)
#define RECOMP2(r, m, d0, d1)                                                           \
    { float4 _a = P8[2 * (m)], _c = P8[2 * (m) + 1];                                    \
      float _dot0 = __fmaf_rn(qz[r], _c.x, __fmaf_rn(qy[r], _a.z, __fmul_rn(qx[r], _a.x))); \
      float _dot1 = __fmaf_rn(qz[r], _c.y, __fmaf_rn(qy[r], _a.w, __fmul_rn(qx[r], _a.y))); \
      d0 = __fsub_rn(__fadd_rn(qw[r], _c.z), __fmul_rn(2.0f, _dot0));                   \
      d1 = __fsub_rn(__fadd_rn(qw[r], _c.w), __fmul_rn(2.0f, _dot1)); }

// PAIR-granular branchless append: one u16 write (pair index) + one
// conditional increment per pair per query. Append iff min(val0,val1) < Tm.
// A pruned pair has BOTH halves approx >= Tm = V16+2M -> exact strictly
// greater than 16 distinct-lane witnesses (2M >> approx err, no ties).
// Non-passing halves of appended pairs are redundant-but-harmless extra
// candidates at expansion (selection is exact over buffer contents).
#define PROC(Av, Cv, mm)                                                                \
    {                                                                                   \
        f32x2 x01 = {(Av).x, (Av).y}, y01 = {(Av).z, (Av).w};                           \
        f32x2 z01 = {(Cv).x, (Cv).y}, sq01 = {(Cv).z, (Cv).w};                          \
        _Pragma("unroll")                                                               \
        for (int r = 0; r < RQ; ++r) {                                                  \
            f32x2 dot01 = __builtin_elementwise_fma(                                    \
                qzv[r], z01, __builtin_elementwise_fma(qyv[r], y01, qxv[r] * x01));     \
            f32x2 val01 = __builtin_elementwise_fma(n2v, dot01, sq01);                  \
            col[wv][r][c[r]][lane] = (u16)(mm);                                         \
            c[r] += (fminf(val01.x, val01.y) < Tm[r]) ? 1 : 0;                          \
        }                                                                               \
    }

#define TRIGC()                                                                         \
    {                                                                                   \
        if (__ballot(c[0] > 16)) tighten(0);                                            \
        if (__ballot(c[1] > 16)) tighten(1);                                            \
    }

// One wave serves RQ=2 rows. Scan: pk-approx conservative filter into per-lane
// LDS pair-columns (branchless); exact RECOMP2 only at tighten/final.
// Invariant: >=16 buffer candidates have exact (d2-qw) <= Tm - MARGIN; every
// prune/discard leaves >=16 strictly-smaller (d2,idx) keys. Final: exact keys.
__global__ __launch_bounds__(256) void knn_kernel(const float4* __restrict__ pos8,
                                                  float* __restrict__ out) {
    __shared__ u16 col[4][RQ][CCAP][64];
    __shared__ u16 dense[4][DCAP];
    const int lane = threadIdx.x & 63;
    const int wv = threadIdx.x >> 6;
    const int rowbase = blockIdx.x * (4 * RQ) + wv * RQ;   // 8 rows per block
    const int b = rowbase >> 13;
    const int ib = rowbase & (NPTS - 1);
    const float4* __restrict__ P8 = pos8 + (size_t)b * NPAIR * 2;
    const u64 below = (1ull << lane) - 1ull;

    float qx[RQ], qy[RQ], qz[RQ], qw[RQ];
    {
        int m = ib >> 1;   // ib even: both rows come from one pair
        float4 a = P8[2 * m], cc = P8[2 * m + 1];
        qx[0] = a.x; qy[0] = a.z; qz[0] = cc.x; qw[0] = cc.z;
        qx[1] = a.y; qy[1] = a.w; qz[1] = cc.y; qw[1] = cc.w;
    }
    f32x2 qxv[RQ], qyv[RQ], qzv[RQ];
#pragma unroll
    for (int r = 0; r < RQ; ++r) {
        qxv[r] = (f32x2){qx[r], qx[r]};
        qyv[r] = (f32x2){qy[r], qy[r]};
        qzv[r] = (f32x2){qz[r], qz[r]};
    }
    const f32x2 n2v = {-2.0f, -2.0f};

    float Tm[RQ];   // filter threshold on approx val (= d2 - qw domain)
    int c[RQ];      // per-lane pair-column count

    // 16th-smallest of 64 per-lane f32 values via bitonic sort + broadcast
    auto rank16f = [&](float v) -> float {
#pragma unroll
        for (int k = 2; k <= 64; k <<= 1)
#pragma unroll
            for (int j = k >> 1; j >= 1; j >>= 1) {
                float o = __shfl_xor(v, j, 64);
                bool up = ((lane & k) == 0) == ((lane & j) == 0);
                v = (up ? (v < o) : (v > o)) ? v : o;
            }
        return __shfl(v, 15, 64);
    };

    // exact tighten: ordK = 16th lane-min of exact candidate ords; compact
    // pairs with min-ord <= ordK; per-lane trim to 16 pairs by pair-min-key
    // (a dropped pair's best half has >=16 smaller candidate keys in-lane).
    auto tighten = [&](int r) {
        u32 mn = 0xFFFFFFFFu;
#pragma unroll
        for (int t = 0; t < CCAP; ++t) {
            if (t < c[r]) {
                u32 m = (u32)col[wv][r][t][lane];
                float d0, d1; RECOMP2(r, m, d0, d1);
                u32 om = f2ord(d0); u32 o1 = f2ord(d1);
                om = o1 < om ? o1 : om;
                mn = om < mn ? om : mn;
            }
        }
        u32 v = mn;
#pragma unroll
        for (int k = 2; k <= 64; k <<= 1)
#pragma unroll
            for (int j = k >> 1; j >= 1; j >>= 1) {
                u32 o = (u32)__shfl_xor((int)v, j, 64);
                bool up = ((lane & k) == 0) == ((lane & j) == 0);
                v = (up ? (v < o) : (v > o)) ? v : o;
            }
        u32 ordK = (u32)__shfl((int)v, 15, 64);
        int nc = 0;
#pragma unroll
        for (int t = 0; t < CCAP; ++t) {
            if (t < c[r]) {
                u32 m = (u32)col[wv][r][t][lane];
                float d0, d1; RECOMP2(r, m, d0, d1);
                u32 om = f2ord(d0); u32 o1 = f2ord(d1);
                om = o1 < om ? o1 : om;
                if (om <= ordK) { col[wv][r][nc][lane] = (u16)m; ++nc; }
            }
        }
        c[r] = nc;
        // trim lane to its 16 smallest pair-min-keys
#pragma unroll 1
        for (int it = 0; it < CCAP - 16; ++it) {
            if (c[r] > 16) {
                u64 mx = 0; int mt = 0;
#pragma unroll
                for (int t = 0; t < CCAP; ++t) {
                    if (t < c[r]) {
                        u32 m = (u32)col[wv][r][t][lane];
                        float d0, d1; RECOMP2(r, m, d0, d1);
                        u32 o0 = f2ord(d0), o1 = f2ord(d1);
                        u64 key = (o1 < o0)
                            ? (((u64)o1 << 13) | (2 * m + 1))
                            : (((u64)o0 << 13) | (2 * m));
                        if (key > mx) { mx = key; mt = t; }
                    }
                }
                col[wv][r][mt][lane] = col[wv][r][c[r] - 1][lane];
                c[r] -= 1;
            }
        }
        Tm[r] = fminf(Tm[r], (ord2f(ordK) - qw[r]) + MARGIN);  // monotone
    };

    // ---- bootstrap: pairs 0..255 (512 cands) fully in registers ----
    {
        float4 A[4], C[4];
#pragma unroll
        for (int s = 0; s < 4; ++s) {
            int m = s * 64 + lane;
            A[s] = P8[2 * m];
            C[s] = P8[2 * m + 1];
        }
#pragma unroll
        for (int r = 0; r < RQ; ++r) {
            f32x2 vv[4];
            float mn = __uint_as_float(0x7f800000u);   // +inf
#pragma unroll
            for (int s = 0; s < 4; ++s) {
                f32x2 x01 = {A[s].x, A[s].y}, y01 = {A[s].z, A[s].w};
                f32x2 z01 = {C[s].x, C[s].y}, sq01 = {C[s].z, C[s].w};
                vv[s] = __builtin_elementwise_fma(
                    n2v, __builtin_elementwise_fma(qzv[r], z01,
                         __builtin_elementwise_fma(qyv[r], y01, qxv[r] * x01)), sq01);
                mn = fminf(mn, fminf(vv[s].x, vv[s].y));
            }
            float V16 = rank16f(mn);
            Tm[r] = V16 + 2.0f * MARGIN;
            c[r] = 0;
#pragma unroll
            for (int s = 0; s < 4; ++s) {
                int m = s * 64 + lane;
                col[wv][r][c[r]][lane] = (u16)m;
                c[r] += (fminf(vv[s].x, vv[s].y) < Tm[r]) ? 1 : 0;
            }
        }
    }

    // ---- steady scan: g = 1..15, 4 pair-slots; trigger check every 2 slots ----
#pragma unroll 1
    for (int g = 1; g < 16; ++g) {
        TRIGC();   // c <= 16 after; +2 pair-writes max before the mid-check
        int base = g * 256;
        float4 A[4], C[4];
#pragma unroll
        for (int s = 0; s < 4; ++s) {
            int m = base + s * 64 + lane;
            A[s] = P8[2 * m];
            C[s] = P8[2 * m + 1];
        }
        PROC(A[0], C[0], base + lane);
        PROC(A[1], C[1], base + 64 + lane);
        TRIGC();   // mid-group check keeps write index < CCAP = 20
        PROC(A[2], C[2], base + 128 + lane);
        PROC(A[3], C[3], base + 192 + lane);
    }

    // ---- final per query (sequential in r -> dense reuse is safe) ----
#pragma unroll
    for (int r = 0; r < RQ; ++r) {
        int sum = c[r];
#pragma unroll
        for (int s2 = 1; s2 < 64; s2 <<= 1) sum += __shfl_xor(sum, s2, 64);
        if (sum > 32) {   // fast path needs 2*pairs <= 64
            tighten(r);
            sum = c[r];
#pragma unroll
            for (int s2 = 1; s2 < 64; s2 <<= 1) sum += __shfl_xor(sum, s2, 64);
        }
        // gather pair entries into dense staging
        int nc = 0;
#pragma unroll 1
        for (int t = 0; t < CCAP; ++t) {
            bool valid = t < c[r];
            u64 bal = __ballot(valid);
            if (!bal) break;
            if (valid) dense[wv][nc + (int)__popcll(bal & below)] = col[wv][r][t][lane];
            nc += (int)__popcll(bal);
        }
        u64 myk = ~0ULL;
        if (nc <= 32) {
            // expand: lane i -> pair dense[i>>1], half i&1; sort-64 exact keys
            bool valid = lane < 2 * nc;
            u32 m = valid ? (u32)dense[wv][lane >> 1] : 0u;
            float d0, d1; RECOMP2(r, m, d0, d1);
            float dd = (lane & 1) ? d1 : d0;
            u64 v = valid ? (((u64)f2ord(dd) << 13) | (2 * m + (lane & 1))) : ~0ULL;
#pragma unroll
            for (int k = 2; k <= 64; k <<= 1)
#pragma unroll
                for (int j = k >> 1; j >= 1; j >>= 1) {
                    u64 o = shflx64(v, j);
                    bool up = ((lane & k) == 0) == ((lane & j) == 0);
                    v = (up ? (v < o) : (v > o)) ? v : o;
                }
            myk = v;   // lane holds rank = lane
        } else {
            // rare path: exact extract-min over <= 256 pairs (512 candidates)
            u64 s8[8];
#pragma unroll
            for (int t = 0; t < 4; ++t) {
                int bi = t * 64 + lane;
                bool valid = bi < nc;
                u32 m = valid ? (u32)dense[wv][bi] : 0u;
                float d0, d1; RECOMP2(r, m, d0, d1);
                s8[2 * t]     = valid ? (((u64)f2ord(d0) << 13) | (2 * m))     : ~0ULL;
                s8[2 * t + 1] = valid ? (((u64)f2ord(d1) << 13) | (2 * m + 1)) : ~0ULL;
            }
#pragma unroll 1
            for (int rr = 0; rr < KNN; ++rr) {
                u64 lm = s8[0];
#pragma unroll
                for (int t = 1; t < 8; ++t) lm = s8[t] < lm ? s8[t] : lm;
                u64 mm = lm;
#pragma unroll
                for (int s2 = 1; s2 < 64; s2 <<= 1) { u64 o = shflx64(mm, s2); mm = o < mm ? o : mm; }
#pragma unroll
                for (int t = 0; t < 8; ++t) s8[t] = (s8[t] == mm) ? ~0ULL : s8[t];
                if (lane == rr) myk = mm;
            }
        }
        if (lane < KNN) {
            int iq = ib + r;
            size_t o1 = (size_t)(b * KNN + lane) * NPTS + iq;
            out[o1] = (float)(u32)(myk & (u64)(NPTS - 1));
            out[(size_t)NB * KNN * NPTS + o1] = ord2f((u32)(myk >> 13));
        }
    }
}

extern "C" void kernel_launch(void* const* d_in, const int* in_sizes, int n_in,
                              void* d_out, int out_size, void* d_ws, size_t ws_size,
                              hipStream_t stream) {
    const float* pos = (const float*)d_in[0];
    float* out = (float*)d_out;
    float4* pos8 = (float4*)d_ws;   // 4*4096*2*16 B = 512 KB scratch

    pack_kernel<<<dim3(NB * NPAIR / 256), dim3(256), 0, stream>>>(pos, pos8);
    knn_kernel<<<dim3(NB * NPTS / 8), dim3(256), 0, stream>>>(pos8, out);
}